// Round 6
// baseline (405.232 us; speedup 1.0000x reference)
//
#include <hip/hip_runtime.h>
#include <hip/hip_bf16.h>
#include <hip/hip_fp16.h>
#include <cstddef>
#include <cstdint>

#define T_ 4
#define B_ 16
#define N_ 512
#define C_ 512
#define H_ 8
#define D_ 64
#define BN_T (B_*N_)   // 8192

typedef unsigned short u16;
typedef __attribute__((ext_vector_type(8))) short bf16x8;       // 8 bf16
typedef __attribute__((ext_vector_type(8))) _Float16 f16x8;     // 8 fp16
typedef __attribute__((ext_vector_type(8))) unsigned short u16x8;
typedef __attribute__((ext_vector_type(4))) float f32x4;

__device__ __forceinline__ u16 f2bf_exact(float f) {
    union { float f; unsigned u; } x; x.f = f; return (u16)(x.u >> 16);
}
// 2-term exact fp16 split: f == h1 + h2/2048 + tail(<=2^-22|f|)
__device__ __forceinline__ void split2(float f, u16& h1, u16& h2) {
    const __half a = __float2half(f);                   // RNE
    const float r = (f - __half2float(a)) * 2048.0f;    // exact (Sterbenz + pow2)
    const __half b = __float2half(r);
    h1 = __half_as_ushort(a); h2 = __half_as_ushort(b);
}
// XOR swizzle, 16B granularity, BYTE offset into a [128][32] fp16 tile (64B rows)
__device__ __forceinline__ int swz(int rr, int q) {
    return (rr << 6) + (((q ^ ((rr >> 1) & 3)) & 3) << 4);
}
// attention LDS swizzle (element index into [64][64] u16 tiles)
__device__ __forceinline__ int SW(int row, int col) {
    return (row << 6) + (col ^ ((row & 7) << 3));
}
// async global->LDS, 16B per lane (dest = uniform base + lane*16)
__device__ __forceinline__ void gload16(const void* g, void* l) {
    __builtin_amdgcn_global_load_lds(
        (const __attribute__((address_space(1))) unsigned int*)g,
        (__attribute__((address_space(3))) unsigned int*)l, 16, 0, 0);
}
// barrier with ONLY lgkm drain: reg-staged LDS producers are fenced, but
// in-flight global prefetch loads (vmcnt) stay outstanding across it.
__device__ __forceinline__ void block_sync_lgkm() {
    __builtin_amdgcn_sched_barrier(0);
    asm volatile("s_waitcnt lgkmcnt(0)" ::: "memory");
    __builtin_amdgcn_s_barrier();
    __builtin_amdgcn_sched_barrier(0);
}

// ---------------------------------------------------------------------------
// x fp32 [T,BN,C] -> tile-major pre-swizzled fp16 splits x1t, x2t.
// ---------------------------------------------------------------------------
__global__ __launch_bounds__(256) void k_split_x(
    const float* __restrict__ x, u16* __restrict__ x1t, u16* __restrict__ x2t)
{
    const int tile = blockIdx.x;            // mt*16 + kb  (4096 tiles)
    const int mt = tile >> 4, kb = tile & 15;
    const int tid = threadIdx.x;
    const int rr = tid >> 1, kh = tid & 1;
    const int t = rr & 3, bn = mt * 32 + (rr >> 2);
    const float* src = x + ((size_t)t * BN_T + bn) * C_ + kb * 32 + kh * 16;
    float f[16];
    *reinterpret_cast<float4*>(f + 0)  = *reinterpret_cast<const float4*>(src + 0);
    *reinterpret_cast<float4*>(f + 4)  = *reinterpret_cast<const float4*>(src + 4);
    *reinterpret_cast<float4*>(f + 8)  = *reinterpret_cast<const float4*>(src + 8);
    *reinterpret_cast<float4*>(f + 12) = *reinterpret_cast<const float4*>(src + 12);
    char* d1 = (char*)(x1t + ((size_t)tile << 12));
    char* d2 = (char*)(x2t + ((size_t)tile << 12));
    #pragma unroll
    for (int j = 0; j < 2; ++j) {
        u16x8 p1, p2;
        #pragma unroll
        for (int e = 0; e < 8; ++e) { u16 h1, h2; split2(f[8*j+e], h1, h2); p1[e] = h1; p2[e] = h2; }
        const int q = 2 * kh + j;
        *reinterpret_cast<u16x8*>(d1 + swz(rr, q)) = p1;
        *reinterpret_cast<u16x8*>(d2 + swz(rr, q)) = p2;
    }
}

// w fp32 [512][512] -> tile-major pre-swizzled fp16 splits
__global__ __launch_bounds__(256) void k_split_w(
    const float* __restrict__ w, u16* __restrict__ w1t, u16* __restrict__ w2t)
{
    const int tile = blockIdx.x;            // nt*16 + kb  (64 tiles)
    const int nt = tile >> 4, kb = tile & 15;
    const int tid = threadIdx.x;
    const int rr = tid >> 1, kh = tid & 1;
    const int c = nt * 128 + rr;
    const float* src = w + (size_t)c * C_ + kb * 32 + kh * 16;
    float f[16];
    *reinterpret_cast<float4*>(f + 0)  = *reinterpret_cast<const float4*>(src + 0);
    *reinterpret_cast<float4*>(f + 4)  = *reinterpret_cast<const float4*>(src + 4);
    *reinterpret_cast<float4*>(f + 8)  = *reinterpret_cast<const float4*>(src + 8);
    *reinterpret_cast<float4*>(f + 12) = *reinterpret_cast<const float4*>(src + 12);
    char* d1 = (char*)(w1t + ((size_t)tile << 12));
    char* d2 = (char*)(w2t + ((size_t)tile << 12));
    #pragma unroll
    for (int j = 0; j < 2; ++j) {
        u16x8 p1, p2;
        #pragma unroll
        for (int e = 0; e < 8; ++e) { u16 h1, h2; split2(f[8*j+e], h1, h2); p1[e] = h1; p2[e] = h2; }
        const int q = 2 * kh + j;
        *reinterpret_cast<u16x8*>(d1 + swz(rr, q)) = p1;
        *reinterpret_cast<u16x8*>(d2 + swz(rr, q)) = p2;
    }
}

// ---------------------------------------------------------------------------
// Merged Q/K/V split-fp16 MFMA Linear -> BN -> LIF(v_th=1) over T=4.
// Grid 3072: lid -> (mt 0..255, ntg 0..11); ntg>>2 selects which linear,
// ntg&3 the 128-col tile. Internals identical to the verified k_linear_mfma.
// ---------------------------------------------------------------------------
__global__ __launch_bounds__(256, 2) void k_linear_qkv(
    const u16* __restrict__ a1t, const u16* __restrict__ a2t,
    const u16* __restrict__ wt_base,
    const float* __restrict__ bi0, const float* __restrict__ ga0, const float* __restrict__ be0,
    const float* __restrict__ mu0, const float* __restrict__ va0,
    const float* __restrict__ bi1, const float* __restrict__ ga1, const float* __restrict__ be1,
    const float* __restrict__ mu1, const float* __restrict__ va1,
    const float* __restrict__ bi2, const float* __restrict__ ga2, const float* __restrict__ be2,
    const float* __restrict__ mu2, const float* __restrict__ va2,
    u16* __restrict__ oq, u16* __restrict__ ok, u16* __restrict__ ov)
{
    __shared__ u16 lds[2][4][4096];   // [buf][A1,A2,B1,B2][8KB tile]

    const int dd  = blockIdx.x;                    // 0..3071
    const int lid = (dd & 7) * 384 + (dd >> 3);    // XCD swizzle (bijective)
    const int mt  = lid / 12;                      // 0..255
    const int ntg = lid - mt * 12;                 // 0..11
    const int li  = ntg >> 2;                      // which linear 0..2
    const int nt  = ntg & 3;
    const int bn0 = mt * 32;
    const int c0  = nt * 128;

    const float* bias  = li == 0 ? bi0 : li == 1 ? bi1 : bi2;
    const float* gamma = li == 0 ? ga0 : li == 1 ? ga1 : ga2;
    const float* beta  = li == 0 ? be0 : li == 1 ? be1 : be2;
    const float* mean  = li == 0 ? mu0 : li == 1 ? mu1 : mu2;
    const float* var   = li == 0 ? va0 : li == 1 ? va1 : va2;
    u16* outp = li == 0 ? oq : li == 1 ? ok : ov;

    const size_t WSZ = (size_t)C_ * C_;
    const u16* w1t = wt_base + (size_t)(2 * li) * WSZ;
    const u16* w2t = wt_base + (size_t)(2 * li + 1) * WSZ;

    const int tid = threadIdx.x;
    const int wv  = tid >> 6, lane = tid & 63;
    const int l15 = tid & 15, g = (tid & 63) >> 4;
    const int go  = wv * 2048 + lane * 16;
    const int lo  = wv * 2048;

    f32x4 accA[2][8], accB[2][8];
    #pragma unroll
    for (int rt = 0; rt < 2; ++rt)
        #pragma unroll
        for (int ct = 0; ct < 8; ++ct) { accA[rt][ct] = {0,0,0,0}; accB[rt][ct] = {0,0,0,0}; }

    const size_t abase = (size_t)mt * 16, bbase = (size_t)nt * 16;

    auto stage = [&](int buf, int kb) {
        char* L = (char*)&lds[buf][0][0];
        const char* ga1p = (const char*)(a1t + ((abase + kb) << 12)) + go;
        const char* ga2p = (const char*)(a2t + ((abase + kb) << 12)) + go;
        const char* gb1 = (const char*)(w1t + ((bbase + kb) << 12)) + go;
        const char* gb2 = (const char*)(w2t + ((bbase + kb) << 12)) + go;
        gload16(ga1p,        L + lo);
        gload16(ga1p + 1024, L + lo + 1024);
        gload16(ga2p,        L + 8192 + lo);
        gload16(ga2p + 1024, L + 8192 + lo + 1024);
        gload16(gb1,        L + 16384 + lo);
        gload16(gb1 + 1024, L + 16384 + lo + 1024);
        gload16(gb2,        L + 24576 + lo);
        gload16(gb2 + 1024, L + 24576 + lo + 1024);
    };

    stage(0, 0);
    __syncthreads();

    #pragma unroll 1
    for (int kb = 0; kb < 16; ++kb) {
        const int buf = kb & 1;
        if (kb < 15) stage(buf ^ 1, kb + 1);
        const char* L = (const char*)&lds[buf][0][0];
        f16x8 a1[2], a2[2];
        #pragma unroll
        for (int rt = 0; rt < 2; ++rt) {
            const int rr = wv * 32 + rt * 16 + l15;
            a1[rt] = *reinterpret_cast<const f16x8*>(L + swz(rr, g));
            a2[rt] = *reinterpret_cast<const f16x8*>(L + 8192 + swz(rr, g));
        }
        #pragma unroll
        for (int ct = 0; ct < 8; ++ct) {
            const int rr2 = ct * 16 + l15;
            const f16x8 b1 = *reinterpret_cast<const f16x8*>(L + 16384 + swz(rr2, g));
            const f16x8 b2 = *reinterpret_cast<const f16x8*>(L + 24576 + swz(rr2, g));
            #pragma unroll
            for (int rt = 0; rt < 2; ++rt) {
                accA[rt][ct] = __builtin_amdgcn_mfma_f32_16x16x32_f16(a1[rt], b1, accA[rt][ct], 0, 0, 0);
                accB[rt][ct] = __builtin_amdgcn_mfma_f32_16x16x32_f16(a2[rt], b1, accB[rt][ct], 0, 0, 0);
                accB[rt][ct] = __builtin_amdgcn_mfma_f32_16x16x32_f16(a1[rt], b2, accB[rt][ct], 0, 0, 0);
            }
        }
        __syncthreads();
    }

    #pragma unroll
    for (int ct = 0; ct < 8; ++ct) {
        const int c = c0 + ct * 16 + l15;
        const float rs = 1.0f / sqrtf(var[c] + 1e-5f);
        const float ga = gamma[c], be = beta[c], mu = mean[c], bi = bias[c];
        #pragma unroll
        for (int rt = 0; rt < 2; ++rt) {
            const int bn = bn0 + wv * 8 + rt * 4 + g;
            float vm = 0.f;
            #pragma unroll
            for (int r = 0; r < 4; ++r) {
                const float y = accA[rt][ct][r] + accB[rt][ct][r] * (1.0f / 2048.0f) + bi;
                const float ybn = (y - mu) * rs * ga + be;
                const float h = vm + (ybn - vm) * 0.5f;
                const bool sp = (h >= 1.0f);
                vm = sp ? 0.f : h;
                const int b = bn >> 9, n = bn & 511;
                const int hh = c >> 6, d2 = c & 63;
                outp[((((size_t)r * B_ + b) * H_ + hh) * N_ + n) * D_ + d2] = sp ? 0x3F80 : 0;
            }
        }
    }
}

// ---------------------------------------------------------------------------
// Final split-fp16 MFMA Linear (spike fp16 input, 2 terms) -> BN -> LIF,
// fp32 0/1 out. Unchanged verified round-4 structure.
// ---------------------------------------------------------------------------
__global__ __launch_bounds__(256, 2) void k_linear_out(
    const u16* __restrict__ a1t,
    const u16* __restrict__ w1t, const u16* __restrict__ w2t,
    const float* __restrict__ bias, const float* __restrict__ gamma,
    const float* __restrict__ beta, const float* __restrict__ mean,
    const float* __restrict__ var, float* __restrict__ outp)
{
    __shared__ u16 lds[2][3][4096];   // [buf][A1,B1,B2]

    const int dd  = blockIdx.x;
    const int lid = (dd & 7) * 128 + (dd >> 3);
    const int mt  = lid >> 2;
    const int nt  = lid & 3;
    const int bn0 = mt * 32;
    const int c0  = nt * 128;

    const int tid = threadIdx.x;
    const int wv  = tid >> 6, lane = tid & 63;
    const int l15 = tid & 15, g = (tid & 63) >> 4;
    const int go  = wv * 2048 + lane * 16;
    const int lo  = wv * 2048;

    f32x4 accA[2][8], accB[2][8];
    #pragma unroll
    for (int rt = 0; rt < 2; ++rt)
        #pragma unroll
        for (int ct = 0; ct < 8; ++ct) { accA[rt][ct] = {0,0,0,0}; accB[rt][ct] = {0,0,0,0}; }

    const size_t abase = (size_t)mt * 16, bbase = (size_t)nt * 16;

    auto stage = [&](int buf, int kb) {
        char* L = (char*)&lds[buf][0][0];
        const char* ga1 = (const char*)(a1t + ((abase + kb) << 12)) + go;
        const char* gb1 = (const char*)(w1t + ((bbase + kb) << 12)) + go;
        const char* gb2 = (const char*)(w2t + ((bbase + kb) << 12)) + go;
        gload16(ga1,        L + lo);
        gload16(ga1 + 1024, L + lo + 1024);
        gload16(gb1,        L + 8192 + lo);
        gload16(gb1 + 1024, L + 8192 + lo + 1024);
        gload16(gb2,        L + 16384 + lo);
        gload16(gb2 + 1024, L + 16384 + lo + 1024);
    };

    stage(0, 0);
    __syncthreads();

    #pragma unroll 1
    for (int kb = 0; kb < 16; ++kb) {
        const int buf = kb & 1;
        if (kb < 15) stage(buf ^ 1, kb + 1);
        const char* L = (const char*)&lds[buf][0][0];
        f16x8 a1[2];
        #pragma unroll
        for (int rt = 0; rt < 2; ++rt) {
            const int rr = wv * 32 + rt * 16 + l15;
            a1[rt] = *reinterpret_cast<const f16x8*>(L + swz(rr, g));
        }
        #pragma unroll
        for (int ct = 0; ct < 8; ++ct) {
            const int rr2 = ct * 16 + l15;
            const f16x8 b1 = *reinterpret_cast<const f16x8*>(L + 8192 + swz(rr2, g));
            const f16x8 b2 = *reinterpret_cast<const f16x8*>(L + 16384 + swz(rr2, g));
            #pragma unroll
            for (int rt = 0; rt < 2; ++rt) {
                accA[rt][ct] = __builtin_amdgcn_mfma_f32_16x16x32_f16(a1[rt], b1, accA[rt][ct], 0, 0, 0);
                accB[rt][ct] = __builtin_amdgcn_mfma_f32_16x16x32_f16(a1[rt], b2, accB[rt][ct], 0, 0, 0);
            }
        }
        __syncthreads();
    }

    #pragma unroll
    for (int ct = 0; ct < 8; ++ct) {
        const int c = c0 + ct * 16 + l15;
        const float rs = 1.0f / sqrtf(var[c] + 1e-5f);
        const float ga = gamma[c], be = beta[c], mu = mean[c], bi = bias[c];
        #pragma unroll
        for (int rt = 0; rt < 2; ++rt) {
            const int bn = bn0 + wv * 8 + rt * 4 + g;
            float vm = 0.f;
            #pragma unroll
            for (int r = 0; r < 4; ++r) {
                const float y = accA[rt][ct][r] + accB[rt][ct][r] * (1.0f / 2048.0f) + bi;
                const float ybn = (y - mu) * rs * ga + be;
                const float h = vm + (ybn - vm) * 0.5f;
                const bool sp = (h >= 1.0f);
                vm = sp ? 0.f : h;
                outp[((size_t)r * BN_T + bn) * C_ + c] = sp ? 1.0f : 0.0f;
            }
        }
    }
}

// ---------------------------------------------------------------------------
// MFMA attention + LIF(0.5): flattened 32-tile pipeline with lgkm-only raw
// barriers (prefetch global loads stay in flight across barriers) and 3-deep
// register prefetch. pv(i) ordered before qk(i+1) so PV's MFMAs aren't
// blocked by QK's S-writes via lgkm counting. Numerics identical (exact).
// ---------------------------------------------------------------------------
__global__ __launch_bounds__(512, 4) void k_attn_mfma(
    const u16* __restrict__ qg, const u16* __restrict__ kg,
    const u16* __restrict__ vg, u16* __restrict__ s2t)
{
    __shared__ u16 ks[2][4096];      // K tiles  [kv][d], swizzled
    __shared__ u16 vts[2][4096];     // V^T tiles [d][kv], swizzled
    __shared__ u16 ssb[8][2][1024];  // per-wave S strips, swizzled

    const int id  = blockIdx.x;                 // 0..511
    const int lid = (id & 7) * 64 + (id >> 3);  // XCD swizzle (bijective)
    const int bh  = lid >> 2;                   // 0..127
    const int qt  = lid & 3;                    // q-tile of 128 rows
    const int b   = bh >> 3, hh = bh & 7;

    const int tid  = threadIdx.x;
    const int w    = tid >> 6, lane = tid & 63;
    const int l15  = lane & 15, g = lane >> 4;

    const bool isK = (tid < 256);               // waves 0-3 stage K, 4-7 stage V
    const int st   = isK ? tid : tid - 256;
    const int krow = st >> 4, kcol = (st & 15) * 4;
    const int vkv  = (st & 15) * 4, vd = (st >> 4) * 4;

    ushort4 pre[2][4];
    bf16x8 qa[2], qpre[2];
    f32x4 vmem[4], oacc[4];
    #pragma unroll
    for (int d0 = 0; d0 < 4; ++d0) { vmem[d0] = {0,0,0,0}; oacc[d0] = {0,0,0,0}; }

    // tile index tl = 0..31 : t = tl>>3, kv-tile j = tl&7
    auto prefetch = [&](int tl) {
        const int t2 = tl >> 3, m0 = (tl & 7) * 64;
        const size_t base2 = ((size_t)t2 * (B_ * H_) + bh) * (size_t)(N_ * D_);
        ushort4* p = pre[tl & 1];
        if (isK) {
            #pragma unroll
            for (int i = 0; i < 4; ++i)
                p[i] = *reinterpret_cast<const ushort4*>(
                    kg + base2 + (size_t)(m0 + krow + 16 * i) * D_ + kcol);
        } else {
            #pragma unroll
            for (int i = 0; i < 4; ++i)
                p[i] = *reinterpret_cast<const ushort4*>(
                    vg + base2 + (size_t)(m0 + vkv + i) * D_ + vd);
        }
        if ((tl & 7) == 0) {
            const size_t qrow = base2 + (size_t)(qt * 128 + 16 * w + l15) * D_;
            qpre[0] = *reinterpret_cast<const bf16x8*>(qg + qrow + 8 * g);
            qpre[1] = *reinterpret_cast<const bf16x8*>(qg + qrow + 32 + 8 * g);
        }
    };
    auto ldswrite = [&](int tl) {
        const int buf = tl & 1;
        const ushort4* p = pre[buf];
        if (isK) {
            #pragma unroll
            for (int i = 0; i < 4; ++i)
                *reinterpret_cast<ushort4*>(&ks[buf][SW(krow + 16 * i, kcol)]) = p[i];
        } else {
            #pragma unroll
            for (int j = 0; j < 4; ++j) {
                ushort4 wv4;
                wv4.x = (&p[0].x)[j]; wv4.y = (&p[1].x)[j];
                wv4.z = (&p[2].x)[j]; wv4.w = (&p[3].x)[j];
                *reinterpret_cast<ushort4*>(&vts[buf][SW(vd + j, vkv)]) = wv4;
            }
        }
    };
    auto qk = [&](int tl) {
        const int buf = tl & 1;
        u16* sb = &ssb[w][buf][0];
        __builtin_amdgcn_s_setprio(1);
        #pragma unroll
        for (int kvt = 0; kvt < 4; ++kvt) {
            f32x4 acc = {0.f, 0.f, 0.f, 0.f};
            #pragma unroll
            for (int c = 0; c < 2; ++c) {
                const bf16x8 kb = *reinterpret_cast<const bf16x8*>(
                    &ks[buf][SW(16 * kvt + l15, 32 * c + 8 * g)]);
                acc = __builtin_amdgcn_mfma_f32_16x16x32_bf16(qa[c], kb, acc, 0, 0, 0);
            }
            #pragma unroll
            for (int r = 0; r < 4; ++r)
                sb[SW(4 * g + r, 16 * kvt + l15)] = f2bf_exact(acc[r]); // int <=64, exact
        }
        __builtin_amdgcn_s_setprio(0);
    };
    auto pv = [&](int tl) {
        const int buf = tl & 1;
        const u16* sb = &ssb[w][buf][0];
        __builtin_amdgcn_s_setprio(1);
        #pragma unroll
        for (int c = 0; c < 2; ++c) {
            const bf16x8 sa = *reinterpret_cast<const bf16x8*>(
                &sb[SW(l15, 32 * c + 8 * g)]);
            #pragma unroll
            for (int d0 = 0; d0 < 4; ++d0) {
                const bf16x8 vb = *reinterpret_cast<const bf16x8*>(
                    &vts[buf][SW(16 * d0 + l15, 32 * c + 8 * g)]);
                oacc[d0] = __builtin_amdgcn_mfma_f32_16x16x32_bf16(sa, vb, oacc[d0], 0, 0, 0);
            }
        }
        __builtin_amdgcn_s_setprio(0);
    };
    auto lif = [&](int t) {
        #pragma unroll
        for (int d0 = 0; d0 < 4; ++d0) {
            const int c = hh * 64 + d0 * 16 + l15;
            const int kb2 = c >> 5, kq = (c >> 3) & 3, e = c & 7;
            #pragma unroll
            for (int r = 0; r < 4; ++r) {
                const float o = oacc[d0][r] * 0.125f;       // pow2, exact
                const float h = vmem[d0][r] + (o - vmem[d0][r]) * 0.5f;
                const bool sp = (h >= 0.5f);
                vmem[d0][r] = sp ? 0.f : h;
                const int n = qt * 128 + 16 * w + 4 * g + r;
                const int bn = b * 512 + n;
                const int mt2 = bn >> 5;
                const int rr2 = (bn & 31) * 4 + t;
                const size_t off = (((size_t)mt2 * 16 + kb2) << 13) + (rr2 << 6)
                                 + (((kq ^ ((rr2 >> 1) & 3)) & 3) << 4) + (e << 1);
                *(u16*)((char*)s2t + off) = sp ? 0x3C00 : 0;   // fp16 1.0
            }
            oacc[d0] = {0.f, 0.f, 0.f, 0.f};
        }
    };

    // prologue: 3-deep prefetch pipeline
    prefetch(0);                     // pre[0] (+ qpre for t=0)
    ldswrite(0);                     // consumes pre[0] (auto vmcnt wait)
    prefetch(1);                     // pre[1]
    prefetch(2);                     // pre[0] (freed)
    qa[0] = qpre[0]; qa[1] = qpre[1];
    block_sync_lgkm();               // ks/vts[0] visible
    qk(0);

    #pragma unroll 1
    for (int i = 0; i < 31; ++i) {
        ldswrite(i + 1);             // consumes pre[(i+1)&1]
        block_sync_lgkm();           // B1: buf (i+1)&1 visible
        if (i < 29) prefetch(i + 3); // refills pre[(i+1)&1]; in flight across barriers
        pv(i);
        if ((i & 7) == 7) lif(i >> 3);
        if (((i + 1) & 7) == 0) { qa[0] = qpre[0]; qa[1] = qpre[1]; }
        qk(i + 1);
        block_sync_lgkm();           // B2: reads of buf i&1 drained before overwrite
    }
    pv(31);
    lif(3);
}

extern "C" void kernel_launch(void* const* d_in, const int* in_sizes, int n_in,
                              void* d_out, int out_size, void* d_ws, size_t ws_size,
                              hipStream_t stream)
{
    const float* x = (const float*)d_in[0];
    const float* W[4]  = {(const float*)d_in[1],  (const float*)d_in[7],  (const float*)d_in[13], (const float*)d_in[19]};
    const float* Bi[4] = {(const float*)d_in[2],  (const float*)d_in[8],  (const float*)d_in[14], (const float*)d_in[20]};
    const float* Ga[4] = {(const float*)d_in[3],  (const float*)d_in[9],  (const float*)d_in[15], (const float*)d_in[21]};
    const float* Be[4] = {(const float*)d_in[4],  (const float*)d_in[10], (const float*)d_in[16], (const float*)d_in[22]};
    const float* Mu[4] = {(const float*)d_in[5],  (const float*)d_in[11], (const float*)d_in[17], (const float*)d_in[23]};
    const float* Va[4] = {(const float*)d_in[6],  (const float*)d_in[12], (const float*)d_in[18], (const float*)d_in[24]};

    const size_t SPK = (size_t)T_ * B_ * N_ * C_;   // 16,777,216
    const size_t WSZ = (size_t)C_ * C_;             // 262,144
    u16* qb  = (u16*)d_ws;          // bf16 spikes [T,B,H,N,D]
    u16* kbf = qb + SPK;
    u16* vbf = kbf + SPK;
    u16* x1t = vbf + SPK;           // tiled x1; reused as s2t after linears
    u16* x2t = x1t + SPK;           // tiled x2
    u16* wt  = x2t + SPK;           // 4 weights x 2 splits x WSZ
    u16* s2t = x1t;                 // attn output overlays x1t (dead by then)

    dim3 blk(256);
    k_split_x<<<4096, blk, 0, stream>>>(x, x1t, x2t);
    for (int i = 0; i < 4; ++i)
        k_split_w<<<64, blk, 0, stream>>>(W[i], wt + (2*i) * WSZ, wt + (2*i+1) * WSZ);

    k_linear_qkv<<<3072, blk, 0, stream>>>(x1t, x2t, wt,
        Bi[0], Ga[0], Be[0], Mu[0], Va[0],
        Bi[1], Ga[1], Be[1], Mu[1], Va[1],
        Bi[2], Ga[2], Be[2], Mu[2], Va[2],
        qb, kbf, vbf);
    k_attn_mfma<<<512, dim3(512), 0, stream>>>(qb, kbf, vbf, s2t);
    k_linear_out<<<1024, blk, 0, stream>>>(s2t, wt + 6*WSZ, wt + 7*WSZ,
        Bi[3], Ga[3], Be[3], Mu[3], Va[3], (float*)d_out);
}

// Round 7
// 382.673 us; speedup vs baseline: 1.0590x; 1.0590x over previous
//
#include <hip/hip_runtime.h>
#include <hip/hip_bf16.h>
#include <hip/hip_fp16.h>
#include <cstddef>
#include <cstdint>

#define T_ 4
#define B_ 16
#define N_ 512
#define C_ 512
#define H_ 8
#define D_ 64
#define BN_T (B_*N_)   // 8192

typedef unsigned short u16;
typedef __attribute__((ext_vector_type(8))) short bf16x8;       // 8 bf16
typedef __attribute__((ext_vector_type(8))) _Float16 f16x8;     // 8 fp16
typedef __attribute__((ext_vector_type(8))) unsigned short u16x8;
typedef __attribute__((ext_vector_type(4))) float f32x4;

__device__ __forceinline__ u16 f2bf_exact(float f) {
    union { float f; unsigned u; } x; x.f = f; return (u16)(x.u >> 16);
}
// 2-term exact fp16 split: f == h1 + h2/2048 + tail(<=2^-22|f|)
__device__ __forceinline__ void split2(float f, u16& h1, u16& h2) {
    const __half a = __float2half(f);                   // RNE
    const float r = (f - __half2float(a)) * 2048.0f;    // exact (Sterbenz + pow2)
    const __half b = __float2half(r);
    h1 = __half_as_ushort(a); h2 = __half_as_ushort(b);
}
// XOR swizzle, 16B granularity, BYTE offset into a [128][32] fp16 tile (64B rows)
__device__ __forceinline__ int swz(int rr, int q) {
    return (rr << 6) + (((q ^ ((rr >> 1) & 3)) & 3) << 4);
}
// attention LDS swizzle (element index into [64][64] u16 tiles)
__device__ __forceinline__ int SW(int row, int col) {
    return (row << 6) + (col ^ ((row & 7) << 3));
}
// async global->LDS, 16B per lane (dest = uniform base + lane*16)
__device__ __forceinline__ void gload16(const void* g, void* l) {
    __builtin_amdgcn_global_load_lds(
        (const __attribute__((address_space(1))) unsigned int*)g,
        (__attribute__((address_space(3))) unsigned int*)l, 16, 0, 0);
}
// barrier with ONLY lgkm drain: reg-staged LDS producers are fenced, but
// in-flight global prefetch loads (vmcnt) stay outstanding across it.
__device__ __forceinline__ void block_sync_lgkm() {
    __builtin_amdgcn_sched_barrier(0);
    asm volatile("s_waitcnt lgkmcnt(0)" ::: "memory");
    __builtin_amdgcn_s_barrier();
    __builtin_amdgcn_sched_barrier(0);
}

// ---------------------------------------------------------------------------
// x fp32 [T,BN,C] -> tile-major pre-swizzled fp16 splits x1t, x2t.
// ---------------------------------------------------------------------------
__global__ __launch_bounds__(256) void k_split_x(
    const float* __restrict__ x, u16* __restrict__ x1t, u16* __restrict__ x2t)
{
    const int tile = blockIdx.x;            // mt*16 + kb  (4096 tiles)
    const int mt = tile >> 4, kb = tile & 15;
    const int tid = threadIdx.x;
    const int rr = tid >> 1, kh = tid & 1;
    const int t = rr & 3, bn = mt * 32 + (rr >> 2);
    const float* src = x + ((size_t)t * BN_T + bn) * C_ + kb * 32 + kh * 16;
    float f[16];
    *reinterpret_cast<float4*>(f + 0)  = *reinterpret_cast<const float4*>(src + 0);
    *reinterpret_cast<float4*>(f + 4)  = *reinterpret_cast<const float4*>(src + 4);
    *reinterpret_cast<float4*>(f + 8)  = *reinterpret_cast<const float4*>(src + 8);
    *reinterpret_cast<float4*>(f + 12) = *reinterpret_cast<const float4*>(src + 12);
    char* d1 = (char*)(x1t + ((size_t)tile << 12));
    char* d2 = (char*)(x2t + ((size_t)tile << 12));
    #pragma unroll
    for (int j = 0; j < 2; ++j) {
        u16x8 p1, p2;
        #pragma unroll
        for (int e = 0; e < 8; ++e) { u16 h1, h2; split2(f[8*j+e], h1, h2); p1[e] = h1; p2[e] = h2; }
        const int q = 2 * kh + j;
        *reinterpret_cast<u16x8*>(d1 + swz(rr, q)) = p1;
        *reinterpret_cast<u16x8*>(d2 + swz(rr, q)) = p2;
    }
}

// w fp32 [512][512] -> tile-major pre-swizzled fp16 splits
__global__ __launch_bounds__(256) void k_split_w(
    const float* __restrict__ w, u16* __restrict__ w1t, u16* __restrict__ w2t)
{
    const int tile = blockIdx.x;            // nt*16 + kb  (64 tiles)
    const int nt = tile >> 4, kb = tile & 15;
    const int tid = threadIdx.x;
    const int rr = tid >> 1, kh = tid & 1;
    const int c = nt * 128 + rr;
    const float* src = w + (size_t)c * C_ + kb * 32 + kh * 16;
    float f[16];
    *reinterpret_cast<float4*>(f + 0)  = *reinterpret_cast<const float4*>(src + 0);
    *reinterpret_cast<float4*>(f + 4)  = *reinterpret_cast<const float4*>(src + 4);
    *reinterpret_cast<float4*>(f + 8)  = *reinterpret_cast<const float4*>(src + 8);
    *reinterpret_cast<float4*>(f + 12) = *reinterpret_cast<const float4*>(src + 12);
    char* d1 = (char*)(w1t + ((size_t)tile << 12));
    char* d2 = (char*)(w2t + ((size_t)tile << 12));
    #pragma unroll
    for (int j = 0; j < 2; ++j) {
        u16x8 p1, p2;
        #pragma unroll
        for (int e = 0; e < 8; ++e) { u16 h1, h2; split2(f[8*j+e], h1, h2); p1[e] = h1; p2[e] = h2; }
        const int q = 2 * kh + j;
        *reinterpret_cast<u16x8*>(d1 + swz(rr, q)) = p1;
        *reinterpret_cast<u16x8*>(d2 + swz(rr, q)) = p2;
    }
}

// ---------------------------------------------------------------------------
// Merged Q/K/V split-fp16 MFMA Linear -> BN -> LIF(v_th=1) over T=4.
// ---------------------------------------------------------------------------
__global__ __launch_bounds__(256, 2) void k_linear_qkv(
    const u16* __restrict__ a1t, const u16* __restrict__ a2t,
    const u16* __restrict__ wt_base,
    const float* __restrict__ bi0, const float* __restrict__ ga0, const float* __restrict__ be0,
    const float* __restrict__ mu0, const float* __restrict__ va0,
    const float* __restrict__ bi1, const float* __restrict__ ga1, const float* __restrict__ be1,
    const float* __restrict__ mu1, const float* __restrict__ va1,
    const float* __restrict__ bi2, const float* __restrict__ ga2, const float* __restrict__ be2,
    const float* __restrict__ mu2, const float* __restrict__ va2,
    u16* __restrict__ oq, u16* __restrict__ ok, u16* __restrict__ ov)
{
    __shared__ u16 lds[2][4][4096];   // [buf][A1,A2,B1,B2][8KB tile]

    const int dd  = blockIdx.x;                    // 0..3071
    const int lid = (dd & 7) * 384 + (dd >> 3);    // XCD swizzle (bijective)
    const int mt  = lid / 12;                      // 0..255
    const int ntg = lid - mt * 12;                 // 0..11
    const int li  = ntg >> 2;                      // which linear 0..2
    const int nt  = ntg & 3;
    const int bn0 = mt * 32;
    const int c0  = nt * 128;

    const float* bias  = li == 0 ? bi0 : li == 1 ? bi1 : bi2;
    const float* gamma = li == 0 ? ga0 : li == 1 ? ga1 : ga2;
    const float* beta  = li == 0 ? be0 : li == 1 ? be1 : be2;
    const float* mean  = li == 0 ? mu0 : li == 1 ? mu1 : mu2;
    const float* var   = li == 0 ? va0 : li == 1 ? va1 : va2;
    u16* outp = li == 0 ? oq : li == 1 ? ok : ov;

    const size_t WSZ = (size_t)C_ * C_;
    const u16* w1t = wt_base + (size_t)(2 * li) * WSZ;
    const u16* w2t = wt_base + (size_t)(2 * li + 1) * WSZ;

    const int tid = threadIdx.x;
    const int wv  = tid >> 6, lane = tid & 63;
    const int l15 = tid & 15, g = (tid & 63) >> 4;
    const int go  = wv * 2048 + lane * 16;
    const int lo  = wv * 2048;

    f32x4 accA[2][8], accB[2][8];
    #pragma unroll
    for (int rt = 0; rt < 2; ++rt)
        #pragma unroll
        for (int ct = 0; ct < 8; ++ct) { accA[rt][ct] = {0,0,0,0}; accB[rt][ct] = {0,0,0,0}; }

    const size_t abase = (size_t)mt * 16, bbase = (size_t)nt * 16;

    auto stage = [&](int buf, int kb) {
        char* L = (char*)&lds[buf][0][0];
        const char* ga1p = (const char*)(a1t + ((abase + kb) << 12)) + go;
        const char* ga2p = (const char*)(a2t + ((abase + kb) << 12)) + go;
        const char* gb1 = (const char*)(w1t + ((bbase + kb) << 12)) + go;
        const char* gb2 = (const char*)(w2t + ((bbase + kb) << 12)) + go;
        gload16(ga1p,        L + lo);
        gload16(ga1p + 1024, L + lo + 1024);
        gload16(ga2p,        L + 8192 + lo);
        gload16(ga2p + 1024, L + 8192 + lo + 1024);
        gload16(gb1,        L + 16384 + lo);
        gload16(gb1 + 1024, L + 16384 + lo + 1024);
        gload16(gb2,        L + 24576 + lo);
        gload16(gb2 + 1024, L + 24576 + lo + 1024);
    };

    stage(0, 0);
    __syncthreads();

    #pragma unroll 1
    for (int kb = 0; kb < 16; ++kb) {
        const int buf = kb & 1;
        if (kb < 15) stage(buf ^ 1, kb + 1);
        const char* L = (const char*)&lds[buf][0][0];
        f16x8 a1[2], a2[2];
        #pragma unroll
        for (int rt = 0; rt < 2; ++rt) {
            const int rr = wv * 32 + rt * 16 + l15;
            a1[rt] = *reinterpret_cast<const f16x8*>(L + swz(rr, g));
            a2[rt] = *reinterpret_cast<const f16x8*>(L + 8192 + swz(rr, g));
        }
        #pragma unroll
        for (int ct = 0; ct < 8; ++ct) {
            const int rr2 = ct * 16 + l15;
            const f16x8 b1 = *reinterpret_cast<const f16x8*>(L + 16384 + swz(rr2, g));
            const f16x8 b2 = *reinterpret_cast<const f16x8*>(L + 24576 + swz(rr2, g));
            #pragma unroll
            for (int rt = 0; rt < 2; ++rt) {
                accA[rt][ct] = __builtin_amdgcn_mfma_f32_16x16x32_f16(a1[rt], b1, accA[rt][ct], 0, 0, 0);
                accB[rt][ct] = __builtin_amdgcn_mfma_f32_16x16x32_f16(a2[rt], b1, accB[rt][ct], 0, 0, 0);
                accB[rt][ct] = __builtin_amdgcn_mfma_f32_16x16x32_f16(a1[rt], b2, accB[rt][ct], 0, 0, 0);
            }
        }
        __syncthreads();
    }

    #pragma unroll
    for (int ct = 0; ct < 8; ++ct) {
        const int c = c0 + ct * 16 + l15;
        const float rs = 1.0f / sqrtf(var[c] + 1e-5f);
        const float ga = gamma[c], be = beta[c], mu = mean[c], bi = bias[c];
        #pragma unroll
        for (int rt = 0; rt < 2; ++rt) {
            const int bn = bn0 + wv * 8 + rt * 4 + g;
            float vm = 0.f;
            #pragma unroll
            for (int r = 0; r < 4; ++r) {
                const float y = accA[rt][ct][r] + accB[rt][ct][r] * (1.0f / 2048.0f) + bi;
                const float ybn = (y - mu) * rs * ga + be;
                const float h = vm + (ybn - vm) * 0.5f;
                const bool sp = (h >= 1.0f);
                vm = sp ? 0.f : h;
                const int b = bn >> 9, n = bn & 511;
                const int hh = c >> 6, d2 = c & 63;
                outp[((((size_t)r * B_ + b) * H_ + hh) * N_ + n) * D_ + d2] = sp ? 0x3F80 : 0;
            }
        }
    }
}

// ---------------------------------------------------------------------------
// Final split-fp16 MFMA Linear (spike fp16 input, 2 terms) -> BN -> LIF,
// fp32 0/1 out.
// ---------------------------------------------------------------------------
__global__ __launch_bounds__(256, 2) void k_linear_out(
    const u16* __restrict__ a1t,
    const u16* __restrict__ w1t, const u16* __restrict__ w2t,
    const float* __restrict__ bias, const float* __restrict__ gamma,
    const float* __restrict__ beta, const float* __restrict__ mean,
    const float* __restrict__ var, float* __restrict__ outp)
{
    __shared__ u16 lds[2][3][4096];   // [buf][A1,B1,B2]

    const int dd  = blockIdx.x;
    const int lid = (dd & 7) * 128 + (dd >> 3);
    const int mt  = lid >> 2;
    const int nt  = lid & 3;
    const int bn0 = mt * 32;
    const int c0  = nt * 128;

    const int tid = threadIdx.x;
    const int wv  = tid >> 6, lane = tid & 63;
    const int l15 = tid & 15, g = (tid & 63) >> 4;
    const int go  = wv * 2048 + lane * 16;
    const int lo  = wv * 2048;

    f32x4 accA[2][8], accB[2][8];
    #pragma unroll
    for (int rt = 0; rt < 2; ++rt)
        #pragma unroll
        for (int ct = 0; ct < 8; ++ct) { accA[rt][ct] = {0,0,0,0}; accB[rt][ct] = {0,0,0,0}; }

    const size_t abase = (size_t)mt * 16, bbase = (size_t)nt * 16;

    auto stage = [&](int buf, int kb) {
        char* L = (char*)&lds[buf][0][0];
        const char* ga1 = (const char*)(a1t + ((abase + kb) << 12)) + go;
        const char* gb1 = (const char*)(w1t + ((bbase + kb) << 12)) + go;
        const char* gb2 = (const char*)(w2t + ((bbase + kb) << 12)) + go;
        gload16(ga1,        L + lo);
        gload16(ga1 + 1024, L + lo + 1024);
        gload16(gb1,        L + 8192 + lo);
        gload16(gb1 + 1024, L + 8192 + lo + 1024);
        gload16(gb2,        L + 16384 + lo);
        gload16(gb2 + 1024, L + 16384 + lo + 1024);
    };

    stage(0, 0);
    __syncthreads();

    #pragma unroll 1
    for (int kb = 0; kb < 16; ++kb) {
        const int buf = kb & 1;
        if (kb < 15) stage(buf ^ 1, kb + 1);
        const char* L = (const char*)&lds[buf][0][0];
        f16x8 a1[2];
        #pragma unroll
        for (int rt = 0; rt < 2; ++rt) {
            const int rr = wv * 32 + rt * 16 + l15;
            a1[rt] = *reinterpret_cast<const f16x8*>(L + swz(rr, g));
        }
        #pragma unroll
        for (int ct = 0; ct < 8; ++ct) {
            const int rr2 = ct * 16 + l15;
            const f16x8 b1 = *reinterpret_cast<const f16x8*>(L + 8192 + swz(rr2, g));
            const f16x8 b2 = *reinterpret_cast<const f16x8*>(L + 16384 + swz(rr2, g));
            #pragma unroll
            for (int rt = 0; rt < 2; ++rt) {
                accA[rt][ct] = __builtin_amdgcn_mfma_f32_16x16x32_f16(a1[rt], b1, accA[rt][ct], 0, 0, 0);
                accB[rt][ct] = __builtin_amdgcn_mfma_f32_16x16x32_f16(a1[rt], b2, accB[rt][ct], 0, 0, 0);
            }
        }
        __syncthreads();
    }

    #pragma unroll
    for (int ct = 0; ct < 8; ++ct) {
        const int c = c0 + ct * 16 + l15;
        const float rs = 1.0f / sqrtf(var[c] + 1e-5f);
        const float ga = gamma[c], be = beta[c], mu = mean[c], bi = bias[c];
        #pragma unroll
        for (int rt = 0; rt < 2; ++rt) {
            const int bn = bn0 + wv * 8 + rt * 4 + g;
            float vm = 0.f;
            #pragma unroll
            for (int r = 0; r < 4; ++r) {
                const float y = accA[rt][ct][r] + accB[rt][ct][r] * (1.0f / 2048.0f) + bi;
                const float ybn = (y - mu) * rs * ga + be;
                const float h = vm + (ybn - vm) * 0.5f;
                const bool sp = (h >= 1.0f);
                vm = sp ? 0.f : h;
                outp[((size_t)r * BN_T + bn) * C_ + c] = sp ? 1.0f : 0.0f;
            }
        }
    }
}

// ---------------------------------------------------------------------------
// MFMA attention + LIF(0.5): flattened 32-tile pipeline, lgkm-only barriers,
// 3-deep register prefetch in two NAMED buffers (preA even tiles, preB odd
// tiles) with the steady loop hand-unrolled x2 so ALL buffer selects are
// compile-time (no scratch — fixes round-6 regression). Numerics exact.
// ---------------------------------------------------------------------------
__global__ __launch_bounds__(512, 4) void k_attn_mfma(
    const u16* __restrict__ qg, const u16* __restrict__ kg,
    const u16* __restrict__ vg, u16* __restrict__ s2t)
{
    __shared__ u16 ks[2][4096];      // K tiles  [kv][d], swizzled
    __shared__ u16 vts[2][4096];     // V^T tiles [d][kv], swizzled
    __shared__ u16 ssb[8][2][1024];  // per-wave S strips, swizzled

    const int id  = blockIdx.x;                 // 0..511
    const int lid = (id & 7) * 64 + (id >> 3);  // XCD swizzle (bijective)
    const int bh  = lid >> 2;                   // 0..127
    const int qt  = lid & 3;                    // q-tile of 128 rows
    const int b   = bh >> 3, hh = bh & 7;

    const int tid  = threadIdx.x;
    const int w    = tid >> 6, lane = tid & 63;
    const int l15  = lane & 15, g = lane >> 4;

    const bool isK = (tid < 256);               // waves 0-3 stage K, 4-7 stage V
    const int st   = isK ? tid : tid - 256;
    const int krow = st >> 4, kcol = (st & 15) * 4;
    const int vkv  = (st & 15) * 4, vd = (st >> 4) * 4;

    ushort4 preA[4], preB[4];        // named buffers -> stay in VGPRs
    bf16x8 qa[2], qpre[2];
    f32x4 vmem[4], oacc[4];
    #pragma unroll
    for (int d0 = 0; d0 < 4; ++d0) { vmem[d0] = {0,0,0,0}; oacc[d0] = {0,0,0,0}; }

    // tile index tl = 0..31 : t = tl>>3, kv-tile j = tl&7
    auto prefetch = [&](int tl, ushort4 (&p)[4]) {
        const int t2 = tl >> 3, m0 = (tl & 7) * 64;
        const size_t base2 = ((size_t)t2 * (B_ * H_) + bh) * (size_t)(N_ * D_);
        if (isK) {
            #pragma unroll
            for (int i = 0; i < 4; ++i)
                p[i] = *reinterpret_cast<const ushort4*>(
                    kg + base2 + (size_t)(m0 + krow + 16 * i) * D_ + kcol);
        } else {
            #pragma unroll
            for (int i = 0; i < 4; ++i)
                p[i] = *reinterpret_cast<const ushort4*>(
                    vg + base2 + (size_t)(m0 + vkv + i) * D_ + vd);
        }
        if ((tl & 7) == 0) {
            const size_t qrow = base2 + (size_t)(qt * 128 + 16 * w + l15) * D_;
            qpre[0] = *reinterpret_cast<const bf16x8*>(qg + qrow + 8 * g);
            qpre[1] = *reinterpret_cast<const bf16x8*>(qg + qrow + 32 + 8 * g);
        }
    };
    auto ldswrite = [&](int buf, const ushort4 (&p)[4]) {   // buf literal at call
        if (isK) {
            #pragma unroll
            for (int i = 0; i < 4; ++i)
                *reinterpret_cast<ushort4*>(&ks[buf][SW(krow + 16 * i, kcol)]) = p[i];
        } else {
            #pragma unroll
            for (int j = 0; j < 4; ++j) {
                ushort4 wv4;
                wv4.x = (&p[0].x)[j]; wv4.y = (&p[1].x)[j];
                wv4.z = (&p[2].x)[j]; wv4.w = (&p[3].x)[j];
                *reinterpret_cast<ushort4*>(&vts[buf][SW(vd + j, vkv)]) = wv4;
            }
        }
    };
    auto qk = [&](int buf) {                                 // buf literal at call
        u16* sb = &ssb[w][buf][0];
        __builtin_amdgcn_s_setprio(1);
        #pragma unroll
        for (int kvt = 0; kvt < 4; ++kvt) {
            f32x4 acc = {0.f, 0.f, 0.f, 0.f};
            #pragma unroll
            for (int c = 0; c < 2; ++c) {
                const bf16x8 kb = *reinterpret_cast<const bf16x8*>(
                    &ks[buf][SW(16 * kvt + l15, 32 * c + 8 * g)]);
                acc = __builtin_amdgcn_mfma_f32_16x16x32_bf16(qa[c], kb, acc, 0, 0, 0);
            }
            #pragma unroll
            for (int r = 0; r < 4; ++r)
                sb[SW(4 * g + r, 16 * kvt + l15)] = f2bf_exact(acc[r]); // int <=64, exact
        }
        __builtin_amdgcn_s_setprio(0);
    };
    auto pv = [&](int buf) {                                 // buf literal at call
        const u16* sb = &ssb[w][buf][0];
        __builtin_amdgcn_s_setprio(1);
        #pragma unroll
        for (int c = 0; c < 2; ++c) {
            const bf16x8 sa = *reinterpret_cast<const bf16x8*>(
                &sb[SW(l15, 32 * c + 8 * g)]);
            #pragma unroll
            for (int d0 = 0; d0 < 4; ++d0) {
                const bf16x8 vb = *reinterpret_cast<const bf16x8*>(
                    &vts[buf][SW(16 * d0 + l15, 32 * c + 8 * g)]);
                oacc[d0] = __builtin_amdgcn_mfma_f32_16x16x32_bf16(sa, vb, oacc[d0], 0, 0, 0);
            }
        }
        __builtin_amdgcn_s_setprio(0);
    };
    auto lif = [&](int t) {
        #pragma unroll
        for (int d0 = 0; d0 < 4; ++d0) {
            const int c = hh * 64 + d0 * 16 + l15;
            const int kb2 = c >> 5, kq = (c >> 3) & 3, e = c & 7;
            #pragma unroll
            for (int r = 0; r < 4; ++r) {
                const float o = oacc[d0][r] * 0.125f;       // pow2, exact
                const float h = vmem[d0][r] + (o - vmem[d0][r]) * 0.5f;
                const bool sp = (h >= 0.5f);
                vmem[d0][r] = sp ? 0.f : h;
                const int n = qt * 128 + 16 * w + 4 * g + r;
                const int bn = b * 512 + n;
                const int mt2 = bn >> 5;
                const int rr2 = (bn & 31) * 4 + t;
                const size_t off = (((size_t)mt2 * 16 + kb2) << 13) + (rr2 << 6)
                                 + (((kq ^ ((rr2 >> 1) & 3)) & 3) << 4) + (e << 1);
                *(u16*)((char*)s2t + off) = sp ? 0x3C00 : 0;   // fp16 1.0
            }
            oacc[d0] = {0.f, 0.f, 0.f, 0.f};
        }
    };

    // prologue: 3-deep prefetch pipeline (tile parity: even->preA/buf0, odd->preB/buf1)
    prefetch(0, preA);               // + qpre for t=0
    ldswrite(0, preA);               // vmcnt handled by reg dependency
    prefetch(1, preB);
    prefetch(2, preA);
    qa[0] = qpre[0]; qa[1] = qpre[1];
    block_sync_lgkm();               // ks/vts[0] visible
    qk(0);

    // steady state, hand-unrolled x2: original iterations io = 0..30;
    // even io consumes/refills preB (odd tiles, buf1), odd io preA (buf0).
    #pragma unroll 1
    for (int i = 0; i < 31; i += 2) {
        // ---- even step io = i ----
        ldswrite(1, preB);           // tile i+1 (odd)
        block_sync_lgkm();           // B1: buf1 visible
        if (i < 29) prefetch(i + 3, preB);   // tile i+3 odd; stays in flight
        pv(0);                        // tile i (even, buf0)
        qk(1);                        // tile i+1 (buf1); no qa reload (i+1 odd)
        block_sync_lgkm();           // B2: buf0 reads drained
        // ---- odd step io = i+1 (skipped when i==30) ----
        if (i + 1 < 31) {
            ldswrite(0, preA);       // tile i+2 (even)
            block_sync_lgkm();       // B1: buf0 visible
            if (i + 1 < 29) prefetch(i + 4, preA);  // tile i+4 even
            pv(1);                    // tile i+1 (buf1)
            if (((i + 1) & 7) == 7) lif((i + 1) >> 3);
            if (((i + 2) & 7) == 0) { qa[0] = qpre[0]; qa[1] = qpre[1]; }
            qk(0);                    // tile i+2 (buf0)
            block_sync_lgkm();       // B2: buf1 reads drained
        }
    }
    pv(1);                            // tile 31 (buf1)
    lif(3);
}

extern "C" void kernel_launch(void* const* d_in, const int* in_sizes, int n_in,
                              void* d_out, int out_size, void* d_ws, size_t ws_size,
                              hipStream_t stream)
{
    const float* x = (const float*)d_in[0];
    const float* W[4]  = {(const float*)d_in[1],  (const float*)d_in[7],  (const float*)d_in[13], (const float*)d_in[19]};
    const float* Bi[4] = {(const float*)d_in[2],  (const float*)d_in[8],  (const float*)d_in[14], (const float*)d_in[20]};
    const float* Ga[4] = {(const float*)d_in[3],  (const float*)d_in[9],  (const float*)d_in[15], (const float*)d_in[21]};
    const float* Be[4] = {(const float*)d_in[4],  (const float*)d_in[10], (const float*)d_in[16], (const float*)d_in[22]};
    const float* Mu[4] = {(const float*)d_in[5],  (const float*)d_in[11], (const float*)d_in[17], (const float*)d_in[23]};
    const float* Va[4] = {(const float*)d_in[6],  (const float*)d_in[12], (const float*)d_in[18], (const float*)d_in[24]};

    const size_t SPK = (size_t)T_ * B_ * N_ * C_;   // 16,777,216
    const size_t WSZ = (size_t)C_ * C_;             // 262,144
    u16* qb  = (u16*)d_ws;          // bf16 spikes [T,B,H,N,D]
    u16* kbf = qb + SPK;
    u16* vbf = kbf + SPK;
    u16* x1t = vbf + SPK;           // tiled x1; reused as s2t after linears
    u16* x2t = x1t + SPK;           // tiled x2
    u16* wt  = x2t + SPK;           // 4 weights x 2 splits x WSZ
    u16* s2t = x1t;                 // attn output overlays x1t (dead by then)

    dim3 blk(256);
    k_split_x<<<4096, blk, 0, stream>>>(x, x1t, x2t);
    for (int i = 0; i < 4; ++i)
        k_split_w<<<64, blk, 0, stream>>>(W[i], wt + (2*i) * WSZ, wt + (2*i+1) * WSZ);

    k_linear_qkv<<<3072, blk, 0, stream>>>(x1t, x2t, wt,
        Bi[0], Ga[0], Be[0], Mu[0], Va[0],
        Bi[1], Ga[1], Be[1], Mu[1], Va[1],
        Bi[2], Ga[2], Be[2], Mu[2], Va[2],
        qb, kbf, vbf);
    k_attn_mfma<<<512, dim3(512), 0, stream>>>(qb, kbf, vbf, s2t);
    k_linear_out<<<1024, blk, 0, stream>>>(s2t, wt + 6*WSZ, wt + 7*WSZ,
        Bi[3], Ga[3], Be[3], Mu[3], Va[3], (float*)d_out);
}

// Round 8
// 303.746 us; speedup vs baseline: 1.3341x; 1.2598x over previous
//
#include <hip/hip_runtime.h>
#include <hip/hip_bf16.h>
#include <hip/hip_fp16.h>
#include <cstddef>
#include <cstdint>

#define T_ 4
#define B_ 16
#define N_ 512
#define C_ 512
#define H_ 8
#define D_ 64
#define BN_T (B_*N_)   // 8192

typedef unsigned short u16;
typedef __attribute__((ext_vector_type(8))) short bf16x8;       // 8 bf16
typedef __attribute__((ext_vector_type(8))) _Float16 f16x8;     // 8 fp16
typedef __attribute__((ext_vector_type(8))) unsigned short u16x8;
typedef __attribute__((ext_vector_type(4))) float f32x4;

__device__ __forceinline__ u16 f2bf_exact(float f) {
    union { float f; unsigned u; } x; x.f = f; return (u16)(x.u >> 16);
}
// 2-term exact fp16 split: f == h1 + h2/2048 + tail(<=2^-22|f|)
__device__ __forceinline__ void split2(float f, u16& h1, u16& h2) {
    const __half a = __float2half(f);                   // RNE
    const float r = (f - __half2float(a)) * 2048.0f;    // exact (Sterbenz + pow2)
    const __half b = __float2half(r);
    h1 = __half_as_ushort(a); h2 = __half_as_ushort(b);
}
// XOR swizzle, 16B granularity, BYTE offset into a [128][32] fp16 tile (64B rows)
__device__ __forceinline__ int swz(int rr, int q) {
    return (rr << 6) + (((q ^ ((rr >> 1) & 3)) & 3) << 4);
}
// attention LDS swizzle (element index into [64][64] u16 tiles)
__device__ __forceinline__ int SW(int row, int col) {
    return (row << 6) + (col ^ ((row & 7) << 3));
}
// async global->LDS, 16B per lane (dest = uniform base + lane*16)
__device__ __forceinline__ void gload16(const void* g, void* l) {
    __builtin_amdgcn_global_load_lds(
        (const __attribute__((address_space(1))) unsigned int*)g,
        (__attribute__((address_space(3))) unsigned int*)l, 16, 0, 0);
}

// ---------------------------------------------------------------------------
// x fp32 [T,BN,C] -> tile-major pre-swizzled fp16 splits x1t, x2t.
// ---------------------------------------------------------------------------
__global__ __launch_bounds__(256) void k_split_x(
    const float* __restrict__ x, u16* __restrict__ x1t, u16* __restrict__ x2t)
{
    const int tile = blockIdx.x;            // mt*16 + kb  (4096 tiles)
    const int mt = tile >> 4, kb = tile & 15;
    const int tid = threadIdx.x;
    const int rr = tid >> 1, kh = tid & 1;
    const int t = rr & 3, bn = mt * 32 + (rr >> 2);
    const float* src = x + ((size_t)t * BN_T + bn) * C_ + kb * 32 + kh * 16;
    float f[16];
    *reinterpret_cast<float4*>(f + 0)  = *reinterpret_cast<const float4*>(src + 0);
    *reinterpret_cast<float4*>(f + 4)  = *reinterpret_cast<const float4*>(src + 4);
    *reinterpret_cast<float4*>(f + 8)  = *reinterpret_cast<const float4*>(src + 8);
    *reinterpret_cast<float4*>(f + 12) = *reinterpret_cast<const float4*>(src + 12);
    char* d1 = (char*)(x1t + ((size_t)tile << 12));
    char* d2 = (char*)(x2t + ((size_t)tile << 12));
    #pragma unroll
    for (int j = 0; j < 2; ++j) {
        u16x8 p1, p2;
        #pragma unroll
        for (int e = 0; e < 8; ++e) { u16 h1, h2; split2(f[8*j+e], h1, h2); p1[e] = h1; p2[e] = h2; }
        const int q = 2 * kh + j;
        *reinterpret_cast<u16x8*>(d1 + swz(rr, q)) = p1;
        *reinterpret_cast<u16x8*>(d2 + swz(rr, q)) = p2;
    }
}

// w fp32 [512][512] -> tile-major pre-swizzled fp16 splits
__global__ __launch_bounds__(256) void k_split_w(
    const float* __restrict__ w, u16* __restrict__ w1t, u16* __restrict__ w2t)
{
    const int tile = blockIdx.x;            // nt*16 + kb  (64 tiles)
    const int nt = tile >> 4, kb = tile & 15;
    const int tid = threadIdx.x;
    const int rr = tid >> 1, kh = tid & 1;
    const int c = nt * 128 + rr;
    const float* src = w + (size_t)c * C_ + kb * 32 + kh * 16;
    float f[16];
    *reinterpret_cast<float4*>(f + 0)  = *reinterpret_cast<const float4*>(src + 0);
    *reinterpret_cast<float4*>(f + 4)  = *reinterpret_cast<const float4*>(src + 4);
    *reinterpret_cast<float4*>(f + 8)  = *reinterpret_cast<const float4*>(src + 8);
    *reinterpret_cast<float4*>(f + 12) = *reinterpret_cast<const float4*>(src + 12);
    char* d1 = (char*)(w1t + ((size_t)tile << 12));
    char* d2 = (char*)(w2t + ((size_t)tile << 12));
    #pragma unroll
    for (int j = 0; j < 2; ++j) {
        u16x8 p1, p2;
        #pragma unroll
        for (int e = 0; e < 8; ++e) { u16 h1, h2; split2(f[8*j+e], h1, h2); p1[e] = h1; p2[e] = h2; }
        const int q = 2 * kh + j;
        *reinterpret_cast<u16x8*>(d1 + swz(rr, q)) = p1;
        *reinterpret_cast<u16x8*>(d2 + swz(rr, q)) = p2;
    }
}

// ---------------------------------------------------------------------------
// Merged Q/K/V split-fp16 MFMA Linear -> BN -> LIF(v_th=1) over T=4.
// ---------------------------------------------------------------------------
__global__ __launch_bounds__(256, 2) void k_linear_qkv(
    const u16* __restrict__ a1t, const u16* __restrict__ a2t,
    const u16* __restrict__ wt_base,
    const float* __restrict__ bi0, const float* __restrict__ ga0, const float* __restrict__ be0,
    const float* __restrict__ mu0, const float* __restrict__ va0,
    const float* __restrict__ bi1, const float* __restrict__ ga1, const float* __restrict__ be1,
    const float* __restrict__ mu1, const float* __restrict__ va1,
    const float* __restrict__ bi2, const float* __restrict__ ga2, const float* __restrict__ be2,
    const float* __restrict__ mu2, const float* __restrict__ va2,
    u16* __restrict__ oq, u16* __restrict__ ok, u16* __restrict__ ov)
{
    __shared__ u16 lds[2][4][4096];   // [buf][A1,A2,B1,B2][8KB tile]

    const int dd  = blockIdx.x;                    // 0..3071
    const int lid = (dd & 7) * 384 + (dd >> 3);    // XCD swizzle (bijective)
    const int mt  = lid / 12;                      // 0..255
    const int ntg = lid - mt * 12;                 // 0..11
    const int li  = ntg >> 2;                      // which linear 0..2
    const int nt  = ntg & 3;
    const int bn0 = mt * 32;
    const int c0  = nt * 128;

    const float* bias  = li == 0 ? bi0 : li == 1 ? bi1 : bi2;
    const float* gamma = li == 0 ? ga0 : li == 1 ? ga1 : ga2;
    const float* beta  = li == 0 ? be0 : li == 1 ? be1 : be2;
    const float* mean  = li == 0 ? mu0 : li == 1 ? mu1 : mu2;
    const float* var   = li == 0 ? va0 : li == 1 ? va1 : va2;
    u16* outp = li == 0 ? oq : li == 1 ? ok : ov;

    const size_t WSZ = (size_t)C_ * C_;
    const u16* w1t = wt_base + (size_t)(2 * li) * WSZ;
    const u16* w2t = wt_base + (size_t)(2 * li + 1) * WSZ;

    const int tid = threadIdx.x;
    const int wv  = tid >> 6, lane = tid & 63;
    const int l15 = tid & 15, g = (tid & 63) >> 4;
    const int go  = wv * 2048 + lane * 16;
    const int lo  = wv * 2048;

    f32x4 accA[2][8], accB[2][8];
    #pragma unroll
    for (int rt = 0; rt < 2; ++rt)
        #pragma unroll
        for (int ct = 0; ct < 8; ++ct) { accA[rt][ct] = {0,0,0,0}; accB[rt][ct] = {0,0,0,0}; }

    const size_t abase = (size_t)mt * 16, bbase = (size_t)nt * 16;

    auto stage = [&](int buf, int kb) {
        char* L = (char*)&lds[buf][0][0];
        const char* ga1p = (const char*)(a1t + ((abase + kb) << 12)) + go;
        const char* ga2p = (const char*)(a2t + ((abase + kb) << 12)) + go;
        const char* gb1 = (const char*)(w1t + ((bbase + kb) << 12)) + go;
        const char* gb2 = (const char*)(w2t + ((bbase + kb) << 12)) + go;
        gload16(ga1p,        L + lo);
        gload16(ga1p + 1024, L + lo + 1024);
        gload16(ga2p,        L + 8192 + lo);
        gload16(ga2p + 1024, L + 8192 + lo + 1024);
        gload16(gb1,        L + 16384 + lo);
        gload16(gb1 + 1024, L + 16384 + lo + 1024);
        gload16(gb2,        L + 24576 + lo);
        gload16(gb2 + 1024, L + 24576 + lo + 1024);
    };

    stage(0, 0);
    __syncthreads();

    #pragma unroll 1
    for (int kb = 0; kb < 16; ++kb) {
        const int buf = kb & 1;
        if (kb < 15) stage(buf ^ 1, kb + 1);
        const char* L = (const char*)&lds[buf][0][0];
        f16x8 a1[2], a2[2];
        #pragma unroll
        for (int rt = 0; rt < 2; ++rt) {
            const int rr = wv * 32 + rt * 16 + l15;
            a1[rt] = *reinterpret_cast<const f16x8*>(L + swz(rr, g));
            a2[rt] = *reinterpret_cast<const f16x8*>(L + 8192 + swz(rr, g));
        }
        #pragma unroll
        for (int ct = 0; ct < 8; ++ct) {
            const int rr2 = ct * 16 + l15;
            const f16x8 b1 = *reinterpret_cast<const f16x8*>(L + 16384 + swz(rr2, g));
            const f16x8 b2 = *reinterpret_cast<const f16x8*>(L + 24576 + swz(rr2, g));
            #pragma unroll
            for (int rt = 0; rt < 2; ++rt) {
                accA[rt][ct] = __builtin_amdgcn_mfma_f32_16x16x32_f16(a1[rt], b1, accA[rt][ct], 0, 0, 0);
                accB[rt][ct] = __builtin_amdgcn_mfma_f32_16x16x32_f16(a2[rt], b1, accB[rt][ct], 0, 0, 0);
                accB[rt][ct] = __builtin_amdgcn_mfma_f32_16x16x32_f16(a1[rt], b2, accB[rt][ct], 0, 0, 0);
            }
        }
        __syncthreads();
    }

    #pragma unroll
    for (int ct = 0; ct < 8; ++ct) {
        const int c = c0 + ct * 16 + l15;
        const float rs = 1.0f / sqrtf(var[c] + 1e-5f);
        const float ga = gamma[c], be = beta[c], mu = mean[c], bi = bias[c];
        #pragma unroll
        for (int rt = 0; rt < 2; ++rt) {
            const int bn = bn0 + wv * 8 + rt * 4 + g;
            float vm = 0.f;
            #pragma unroll
            for (int r = 0; r < 4; ++r) {
                const float y = accA[rt][ct][r] + accB[rt][ct][r] * (1.0f / 2048.0f) + bi;
                const float ybn = (y - mu) * rs * ga + be;
                const float h = vm + (ybn - vm) * 0.5f;
                const bool sp = (h >= 1.0f);
                vm = sp ? 0.f : h;
                const int b = bn >> 9, n = bn & 511;
                const int hh = c >> 6, d2 = c & 63;
                outp[((((size_t)r * B_ + b) * H_ + hh) * N_ + n) * D_ + d2] = sp ? 0x3F80 : 0;
            }
        }
    }
}

// ---------------------------------------------------------------------------
// Final split-fp16 MFMA Linear (spike fp16 input, 2 terms) -> BN -> LIF,
// fp32 0/1 out.
// ---------------------------------------------------------------------------
__global__ __launch_bounds__(256, 2) void k_linear_out(
    const u16* __restrict__ a1t,
    const u16* __restrict__ w1t, const u16* __restrict__ w2t,
    const float* __restrict__ bias, const float* __restrict__ gamma,
    const float* __restrict__ beta, const float* __restrict__ mean,
    const float* __restrict__ var, float* __restrict__ outp)
{
    __shared__ u16 lds[2][3][4096];   // [buf][A1,B1,B2]

    const int dd  = blockIdx.x;
    const int lid = (dd & 7) * 128 + (dd >> 3);
    const int mt  = lid >> 2;
    const int nt  = lid & 3;
    const int bn0 = mt * 32;
    const int c0  = nt * 128;

    const int tid = threadIdx.x;
    const int wv  = tid >> 6, lane = tid & 63;
    const int l15 = tid & 15, g = (tid & 63) >> 4;
    const int go  = wv * 2048 + lane * 16;
    const int lo  = wv * 2048;

    f32x4 accA[2][8], accB[2][8];
    #pragma unroll
    for (int rt = 0; rt < 2; ++rt)
        #pragma unroll
        for (int ct = 0; ct < 8; ++ct) { accA[rt][ct] = {0,0,0,0}; accB[rt][ct] = {0,0,0,0}; }

    const size_t abase = (size_t)mt * 16, bbase = (size_t)nt * 16;

    auto stage = [&](int buf, int kb) {
        char* L = (char*)&lds[buf][0][0];
        const char* ga1 = (const char*)(a1t + ((abase + kb) << 12)) + go;
        const char* gb1 = (const char*)(w1t + ((bbase + kb) << 12)) + go;
        const char* gb2 = (const char*)(w2t + ((bbase + kb) << 12)) + go;
        gload16(ga1,        L + lo);
        gload16(ga1 + 1024, L + lo + 1024);
        gload16(gb1,        L + 8192 + lo);
        gload16(gb1 + 1024, L + 8192 + lo + 1024);
        gload16(gb2,        L + 16384 + lo);
        gload16(gb2 + 1024, L + 16384 + lo + 1024);
    };

    stage(0, 0);
    __syncthreads();

    #pragma unroll 1
    for (int kb = 0; kb < 16; ++kb) {
        const int buf = kb & 1;
        if (kb < 15) stage(buf ^ 1, kb + 1);
        const char* L = (const char*)&lds[buf][0][0];
        f16x8 a1[2];
        #pragma unroll
        for (int rt = 0; rt < 2; ++rt) {
            const int rr = wv * 32 + rt * 16 + l15;
            a1[rt] = *reinterpret_cast<const f16x8*>(L + swz(rr, g));
        }
        #pragma unroll
        for (int ct = 0; ct < 8; ++ct) {
            const int rr2 = ct * 16 + l15;
            const f16x8 b1 = *reinterpret_cast<const f16x8*>(L + 8192 + swz(rr2, g));
            const f16x8 b2 = *reinterpret_cast<const f16x8*>(L + 16384 + swz(rr2, g));
            #pragma unroll
            for (int rt = 0; rt < 2; ++rt) {
                accA[rt][ct] = __builtin_amdgcn_mfma_f32_16x16x32_f16(a1[rt], b1, accA[rt][ct], 0, 0, 0);
                accB[rt][ct] = __builtin_amdgcn_mfma_f32_16x16x32_f16(a1[rt], b2, accB[rt][ct], 0, 0, 0);
            }
        }
        __syncthreads();
    }

    #pragma unroll
    for (int ct = 0; ct < 8; ++ct) {
        const int c = c0 + ct * 16 + l15;
        const float rs = 1.0f / sqrtf(var[c] + 1e-5f);
        const float ga = gamma[c], be = beta[c], mu = mean[c], bi = bias[c];
        #pragma unroll
        for (int rt = 0; rt < 2; ++rt) {
            const int bn = bn0 + wv * 8 + rt * 4 + g;
            float vm = 0.f;
            #pragma unroll
            for (int r = 0; r < 4; ++r) {
                const float y = accA[rt][ct][r] + accB[rt][ct][r] * (1.0f / 2048.0f) + bi;
                const float ybn = (y - mu) * rs * ga + be;
                const float h = vm + (ybn - vm) * 0.5f;
                const bool sp = (h >= 1.0f);
                vm = sp ? 0.f : h;
                outp[((size_t)r * BN_T + bn) * C_ + c] = sp ? 1.0f : 0.0f;
            }
        }
    }
}

// ---------------------------------------------------------------------------
// MFMA attention + LIF(0.5), whole-KV-in-LDS structure:
// Block = 8 waves, one (bh, qt=128 q-rows). Per t: stage ALL of K (64KB,
// coalesced 16B chunks) and V^T (64KB, 4x4 register transpose) into LDS once,
// one barrier, then 8 KV tiles with NO barriers (kf/vf read-only, S strip
// wave-private, per-wave LDS ops are in-order). qk/pv interleaved at
// half-tile granularity to shorten the S round-trip. 2 barriers per t total.
// All arithmetic exact as verified in rounds 2-7 (same MFMA/S/LIF code).
// ---------------------------------------------------------------------------
__global__ __launch_bounds__(512, 2) void k_attn_mfma(
    const u16* __restrict__ qg, const u16* __restrict__ kg,
    const u16* __restrict__ vg, u16* __restrict__ s2t)
{
    __shared__ u16 kf[8][4096];    // full K  [jt][SW(kv,d)]   64KB
    __shared__ u16 vf[8][4096];    // full V^T [jt][SW(d,kv)]  64KB
    __shared__ u16 ssb[8][1024];   // per-wave S strip (16x64) 16KB

    const int id  = blockIdx.x;                 // 0..511
    const int lid = (id & 7) * 64 + (id >> 3);  // XCD swizzle; qt-siblings same XCD
    const int bh  = lid >> 2;                   // 0..127
    const int qt  = lid & 3;                    // 128-row q tile
    const int b   = bh >> 3, hh = bh & 7;

    const int tid  = threadIdx.x;
    const int w    = tid >> 6, lane = tid & 63;
    const int l15  = lane & 15, g = lane >> 4;

    // V staging coords (4 slots/thread, 4x4 transpose each)
    const int vkv = (tid & 15) * 4;
    const int vd  = ((tid >> 4) & 15) * 4;

    bf16x8 qa[2];
    f32x4 vmem[4], oacc[4];
    #pragma unroll
    for (int d0 = 0; d0 < 4; ++d0) { vmem[d0] = {0,0,0,0}; oacc[d0] = {0,0,0,0}; }

    #pragma unroll 1
    for (int t = 0; t < T_; ++t) {
        const size_t base = ((size_t)t * (B_ * H_) + bh) * (size_t)(N_ * D_);
        if (t > 0) __syncthreads();            // readers of t-1 done

        // ---- Q fragments for this t (issued first, returns during staging) ----
        {
            const size_t qrow = base + (size_t)(qt * 128 + 16 * w + l15) * D_;
            qa[0] = *reinterpret_cast<const bf16x8*>(qg + qrow + 8 * g);
            qa[1] = *reinterpret_cast<const bf16x8*>(qg + qrow + 32 + 8 * g);
        }
        // ---- stage K: 8 coalesced 16B chunks/thread; jt == i (compile-time) ----
        {
            const u16* kb = kg + base;
            #pragma unroll
            for (int i = 0; i < 8; ++i) {
                const int r64 = tid >> 3;              // row within tile
                const int col = (tid & 7) * 8;
                const u16x8 v = *reinterpret_cast<const u16x8*>(kb + ((size_t)(tid + 512 * i)) * 8);
                *reinterpret_cast<u16x8*>(&kf[i][SW(r64, col)]) = v;
            }
        }
        // ---- stage V^T: 4 slots/thread, 4x4 register transpose ----
        {
            const u16* vb = vg + base;
            #pragma unroll
            for (int i = 0; i < 4; ++i) {
                const int jt = 2 * i + (tid >> 8);     // slot tile
                const int m0 = jt * 64;
                ushort4 r0 = *reinterpret_cast<const ushort4*>(vb + (size_t)(m0 + vkv + 0) * D_ + vd);
                ushort4 r1 = *reinterpret_cast<const ushort4*>(vb + (size_t)(m0 + vkv + 1) * D_ + vd);
                ushort4 r2 = *reinterpret_cast<const ushort4*>(vb + (size_t)(m0 + vkv + 2) * D_ + vd);
                ushort4 r3 = *reinterpret_cast<const ushort4*>(vb + (size_t)(m0 + vkv + 3) * D_ + vd);
                ushort4 wv4;
                wv4.x = r0.x; wv4.y = r1.x; wv4.z = r2.x; wv4.w = r3.x;
                *reinterpret_cast<ushort4*>(&vf[jt][SW(vd + 0, vkv)]) = wv4;
                wv4.x = r0.y; wv4.y = r1.y; wv4.z = r2.y; wv4.w = r3.y;
                *reinterpret_cast<ushort4*>(&vf[jt][SW(vd + 1, vkv)]) = wv4;
                wv4.x = r0.z; wv4.y = r1.z; wv4.z = r2.z; wv4.w = r3.z;
                *reinterpret_cast<ushort4*>(&vf[jt][SW(vd + 2, vkv)]) = wv4;
                wv4.x = r0.w; wv4.y = r1.w; wv4.z = r2.w; wv4.w = r3.w;
                *reinterpret_cast<ushort4*>(&vf[jt][SW(vd + 3, vkv)]) = wv4;
            }
        }
        __syncthreads();                        // staged K/V visible

        // ---- 8 KV tiles, no barriers ----
        u16* sb = &ssb[w][0];
        #pragma unroll
        for (int jt = 0; jt < 8; ++jt) {
            __builtin_amdgcn_s_setprio(1);
            // qk half 1: kvt 0,1 -> S cols 0..31
            #pragma unroll
            for (int kvt = 0; kvt < 2; ++kvt) {
                f32x4 acc = {0.f, 0.f, 0.f, 0.f};
                #pragma unroll
                for (int c = 0; c < 2; ++c) {
                    const bf16x8 kb = *reinterpret_cast<const bf16x8*>(
                        &kf[jt][SW(16 * kvt + l15, 32 * c + 8 * g)]);
                    acc = __builtin_amdgcn_mfma_f32_16x16x32_bf16(qa[c], kb, acc, 0, 0, 0);
                }
                #pragma unroll
                for (int r = 0; r < 4; ++r)
                    sb[SW(4 * g + r, 16 * kvt + l15)] = f2bf_exact(acc[r]); // int <=64
            }
            // pv half 1: c=0 reads S cols 0..31
            {
                const bf16x8 sa = *reinterpret_cast<const bf16x8*>(&sb[SW(l15, 8 * g)]);
                #pragma unroll
                for (int d0 = 0; d0 < 4; ++d0) {
                    const bf16x8 vb2 = *reinterpret_cast<const bf16x8*>(
                        &vf[jt][SW(16 * d0 + l15, 8 * g)]);
                    oacc[d0] = __builtin_amdgcn_mfma_f32_16x16x32_bf16(sa, vb2, oacc[d0], 0, 0, 0);
                }
            }
            // qk half 2: kvt 2,3 -> S cols 32..63
            #pragma unroll
            for (int kvt = 2; kvt < 4; ++kvt) {
                f32x4 acc = {0.f, 0.f, 0.f, 0.f};
                #pragma unroll
                for (int c = 0; c < 2; ++c) {
                    const bf16x8 kb = *reinterpret_cast<const bf16x8*>(
                        &kf[jt][SW(16 * kvt + l15, 32 * c + 8 * g)]);
                    acc = __builtin_amdgcn_mfma_f32_16x16x32_bf16(qa[c], kb, acc, 0, 0, 0);
                }
                #pragma unroll
                for (int r = 0; r < 4; ++r)
                    sb[SW(4 * g + r, 16 * kvt + l15)] = f2bf_exact(acc[r]);
            }
            // pv half 2: c=1 reads S cols 32..63
            {
                const bf16x8 sa = *reinterpret_cast<const bf16x8*>(&sb[SW(l15, 32 + 8 * g)]);
                #pragma unroll
                for (int d0 = 0; d0 < 4; ++d0) {
                    const bf16x8 vb2 = *reinterpret_cast<const bf16x8*>(
                        &vf[jt][SW(16 * d0 + l15, 32 + 8 * g)]);
                    oacc[d0] = __builtin_amdgcn_mfma_f32_16x16x32_bf16(sa, vb2, oacc[d0], 0, 0, 0);
                }
            }
            __builtin_amdgcn_s_setprio(0);
        }

        // ---- LIF (v_th=0.5); 0.125 folded here (pow2, exact); tiled s2t out ----
        #pragma unroll
        for (int d0 = 0; d0 < 4; ++d0) {
            const int c = hh * 64 + d0 * 16 + l15;
            const int kb2 = c >> 5, kq = (c >> 3) & 3, e = c & 7;
            #pragma unroll
            for (int r = 0; r < 4; ++r) {
                const float o = oacc[d0][r] * 0.125f;
                const float h = vmem[d0][r] + (o - vmem[d0][r]) * 0.5f;
                const bool sp = (h >= 0.5f);
                vmem[d0][r] = sp ? 0.f : h;
                const int n = qt * 128 + 16 * w + 4 * g + r;
                const int bn = b * 512 + n;
                const int mt2 = bn >> 5;
                const int rr2 = (bn & 31) * 4 + t;
                const size_t off = (((size_t)mt2 * 16 + kb2) << 13) + (rr2 << 6)
                                 + (((kq ^ ((rr2 >> 1) & 3)) & 3) << 4) + (e << 1);
                *(u16*)((char*)s2t + off) = sp ? 0x3C00 : 0;   // fp16 1.0
            }
            oacc[d0] = {0.f, 0.f, 0.f, 0.f};
        }
    }
}

extern "C" void kernel_launch(void* const* d_in, const int* in_sizes, int n_in,
                              void* d_out, int out_size, void* d_ws, size_t ws_size,
                              hipStream_t stream)
{
    const float* x = (const float*)d_in[0];
    const float* W[4]  = {(const float*)d_in[1],  (const float*)d_in[7],  (const float*)d_in[13], (const float*)d_in[19]};
    const float* Bi[4] = {(const float*)d_in[2],  (const float*)d_in[8],  (const float*)d_in[14], (const float*)d_in[20]};
    const float* Ga[4] = {(const float*)d_in[3],  (const float*)d_in[9],  (const float*)d_in[15], (const float*)d_in[21]};
    const float* Be[4] = {(const float*)d_in[4],  (const float*)d_in[10], (const float*)d_in[16], (const float*)d_in[22]};
    const float* Mu[4] = {(const float*)d_in[5],  (const float*)d_in[11], (const float*)d_in[17], (const float*)d_in[23]};
    const float* Va[4] = {(const float*)d_in[6],  (const float*)d_in[12], (const float*)d_in[18], (const float*)d_in[24]};

    const size_t SPK = (size_t)T_ * B_ * N_ * C_;   // 16,777,216
    const size_t WSZ = (size_t)C_ * C_;             // 262,144
    u16* qb  = (u16*)d_ws;          // bf16 spikes [T,B,H,N,D]
    u16* kbf = qb + SPK;
    u16* vbf = kbf + SPK;
    u16* x1t = vbf + SPK;           // tiled x1; reused as s2t after linears
    u16* x2t = x1t + SPK;           // tiled x2
    u16* wt  = x2t + SPK;           // 4 weights x 2 splits x WSZ
    u16* s2t = x1t;                 // attn output overlays x1t (dead by then)

    dim3 blk(256);
    k_split_x<<<4096, blk, 0, stream>>>(x, x1t, x2t);
    for (int i = 0; i < 4; ++i)
        k_split_w<<<64, blk, 0, stream>>>(W[i], wt + (2*i) * WSZ, wt + (2*i+1) * WSZ);

    k_linear_qkv<<<3072, blk, 0, stream>>>(x1t, x2t, wt,
        Bi[0], Ga[0], Be[0], Mu[0], Va[0],
        Bi[1], Ga[1], Be[1], Mu[1], Va[1],
        Bi[2], Ga[2], Be[2], Mu[2], Va[2],
        qb, kbf, vbf);
    k_attn_mfma<<<512, dim3(512), 0, stream>>>(qb, kbf, vbf, s2t);
    k_linear_out<<<1024, blk, 0, stream>>>(s2t, wt + 6*WSZ, wt + 7*WSZ,
        Bi[3], Ga[3], Be[3], Mu[3], Va[3], (float*)d_out);
}